// Round 2
// baseline (724.399 us; speedup 1.0000x reference)
//
#include <hip/hip_runtime.h>

typedef _Float16 f16x8 __attribute__((ext_vector_type(8)));
typedef _Float16 f16x4 __attribute__((ext_vector_type(4)));
typedef float f32x4 __attribute__((ext_vector_type(4)));

// LDS: x-tile A[64][264] f16 (33792 B), later reused as ao[64][264].
// Stride 264 f16 = 528 B = 132 banks ≡ 4 mod 32 → b128 row reads are 2-way (free).
#define A_STRIDE 264
#define LDS_BYTES (64 * A_STRIDE * 2)

__device__ __forceinline__ float packh2(float x, float y) {
  union { float f; _Float16 h[2]; } u;
  u.h[0] = (_Float16)x; u.h[1] = (_Float16)y;
  return u.f;
}

// Quad-regroup: source C-layout regs hold X[R][L] with R = 16*mt + 4*quad + r,
// L = lane&15. lo*/hi* are packed pairs (r=0,1 | r=2,3) of tiles mt=2kk and 2kk+1.
// Returns operand frag: lane (c16,q) gets X[32kk + 8q + j][c16], j=0..7.
__device__ __forceinline__ f16x8 regroup(float lo0, float lo1, float hi0, float hi1,
                                         int c16, int q) {
  int sA = c16 | ((q & 1) << 5);   // lane c16 + 16*(2*(q&1))   -> j=0..3
  int sB = sA | 16;                // lane c16 + 16*(2*(q&1)+1) -> j=4..7
  float a0 = __shfl(lo0, sA), a1 = __shfl(lo1, sA);
  float a2 = __shfl(hi0, sA), a3 = __shfl(hi1, sA);
  float b0 = __shfl(lo0, sB), b1 = __shfl(lo1, sB);
  float b2 = __shfl(hi0, sB), b3 = __shfl(hi1, sB);
  bool hi = q >= 2;                // mt = 2kk + (q>>1)
  float4 f;
  f.x = hi ? a2 : a0; f.y = hi ? a3 : a1;
  f.z = hi ? b2 : b0; f.w = hi ? b3 : b1;
  union { float4 v; f16x8 h; } u; u.v = f;
  return u.h;
}

__global__ __launch_bounds__(256) void convert_weights_kernel(
    const float* __restrict__ wqkv, const float* __restrict__ wproj,
    _Float16* __restrict__ dst) {
  int i = blockIdx.x * 256 + threadIdx.x;   // 65536 threads, 4 floats each
  float4 v;
  if (i < 49152) v = ((const float4*)wqkv)[i];
  else           v = ((const float4*)wproj)[i - 49152];
  f16x4 h;
  h[0] = (_Float16)v.x; h[1] = (_Float16)v.y;
  h[2] = (_Float16)v.z; h[3] = (_Float16)v.w;
  *(f16x4*)&dst[4 * i] = h;
}

__global__ __launch_bounds__(512, 4) void win_attn_kernel(
    const float* __restrict__ x, const _Float16* __restrict__ Wh,
    const float* __restrict__ bqkv, const float* __restrict__ bproj,
    float* __restrict__ out)
{
  __shared__ __align__(16) char smem[LDS_BYTES];
  _Float16* A = (_Float16*)smem;

  const int tid  = threadIdx.x;
  const int lane = tid & 63;
  const int wv   = tid >> 6;      // wave id == head id
  const int c16  = lane & 15;
  const int q    = lane >> 4;     // quad 0..3

  // XCD-pair swizzle: block ids g*16+s and g*16+s+8 (same XCD under mod-8 rr)
  // map to horizontally adjacent windows 2j, 2j+1 (they share 64-B x lines).
  const int id = blockIdx.x;
  const int g = id >> 4, s = id & 15;
  const int w = (g << 4) | ((s & 7) << 1) | (s >> 3);
  const int b  = w >> 8;
  const int hn = (w >> 4) & 15;
  const int wn = w & 15;
  const size_t xbase = (size_t)b * (256 * 16384) + (size_t)(hn * 8) * 128 + (size_t)(wn * 8);

  // ---- stage 1: x window -> A f16 [token][channel], float4 loads ----
  // lane -> (pq = channel-pair subgroup, i = window row, jj = float4 within row)
  {
    const int pq = lane >> 4;          // 0..3
    const int i  = (lane >> 1) & 7;    // row 0..7
    const int jj = lane & 1;           // 0..1
    const size_t sp = xbase + (size_t)i * 128 + jj * 4;
    #pragma unroll
    for (int ss = 0; ss < 4; ++ss) {
      int c = wv * 32 + (ss * 4 + pq) * 2;
      float4 v0 = *(const float4*)&x[sp + (size_t)c * 16384];
      float4 v1 = *(const float4*)&x[sp + (size_t)(c + 1) * 16384];
      int t0 = i * 8 + jj * 4;
      *(float*)&A[(t0 + 0) * A_STRIDE + c] = packh2(v0.x, v1.x);
      *(float*)&A[(t0 + 1) * A_STRIDE + c] = packh2(v0.y, v1.y);
      *(float*)&A[(t0 + 2) * A_STRIDE + c] = packh2(v0.z, v1.z);
      *(float*)&A[(t0 + 3) * A_STRIDE + c] = packh2(v0.w, v1.w);
    }
  }
  __syncthreads();

  // ---- stage 2b FIRST: v via token-major GEMM  D[t][d] = x . W_v^T ----
  // (only vf, 16 VGPRs, stays live across the QK GEMMs — not qf/kf's 32)
  f16x8 vf[2][2];   // [d-tile][kk]: V^T frags, lane&15 = d, regs = u (8q+j)
  {
    f32x4 av[4][2];   // [mu][nd]
    #pragma unroll
    for (int mu = 0; mu < 4; ++mu)
      #pragma unroll
      for (int nd = 0; nd < 2; ++nd)
        av[mu][nd] = (f32x4){0.f,0.f,0.f,0.f};
    const _Float16* Wv = Wh + (size_t)(512 + 32 * wv) * 256;
    __builtin_amdgcn_s_setprio(1);
    #pragma unroll
    for (int k0 = 0; k0 < 8; ++k0) {
      f16x8 xf[4];
      #pragma unroll
      for (int mu = 0; mu < 4; ++mu)
        xf[mu] = *(const f16x8*)&A[(mu * 16 + c16) * A_STRIDE + k0 * 32 + q * 8];
      f16x8 wv0 = *(const f16x8*)&Wv[(c16) * 256 + k0 * 32 + q * 8];
      f16x8 wv1 = *(const f16x8*)&Wv[(16 + c16) * 256 + k0 * 32 + q * 8];
      #pragma unroll
      for (int mu = 0; mu < 4; ++mu) {
        av[mu][0] = __builtin_amdgcn_mfma_f32_16x16x32_f16(xf[mu], wv0, av[mu][0], 0, 0, 0);
        av[mu][1] = __builtin_amdgcn_mfma_f32_16x16x32_f16(xf[mu], wv1, av[mu][1], 0, 0, 0);
      }
    }
    __builtin_amdgcn_s_setprio(0);
    #pragma unroll
    for (int nd = 0; nd < 2; ++nd) {
      float bv = bqkv[512 + 32 * wv + nd * 16 + c16];   // d = c16+16nd (lane-low)
      #pragma unroll
      for (int mu = 0; mu < 4; ++mu) {
        av[mu][nd][0] += bv; av[mu][nd][1] += bv; av[mu][nd][2] += bv; av[mu][nd][3] += bv;
      }
      float pv[4][2];
      #pragma unroll
      for (int mu = 0; mu < 4; ++mu) {
        pv[mu][0] = packh2(av[mu][nd][0], av[mu][nd][1]);
        pv[mu][1] = packh2(av[mu][nd][2], av[mu][nd][3]);
      }
      #pragma unroll
      for (int kk = 0; kk < 2; ++kk)
        vf[nd][kk] = regroup(pv[2*kk][0], pv[2*kk][1], pv[2*kk+1][0], pv[2*kk+1][1], c16, q);
    }
  }

  // ---- stage 2a: q then k via swapped GEMM  D[d][t] = W . x^T ----
  // Sequential Q-pass / K-pass: halves live accumulators (32 not 64) so peak
  // liveness stays ~100 VGPRs, safely under the 128 cap. Costs one extra
  // sweep of 32 ds_read_b128/wave on a mostly-idle LDS pipe.
  f16x8 qf[4], kf[4];   // operand frags: lane&15 = token, regs = d (8q+j)
  #pragma unroll
  for (int pass = 0; pass < 2; ++pass) {
    f32x4 ac[2][4];   // [md][nt]
    #pragma unroll
    for (int md = 0; md < 2; ++md)
      #pragma unroll
      for (int nt = 0; nt < 4; ++nt)
        ac[md][nt] = (f32x4){0.f,0.f,0.f,0.f};
    const _Float16* Wx = Wh + (size_t)(256 * pass + 32 * wv) * 256;
    __builtin_amdgcn_s_setprio(1);
    #pragma unroll
    for (int k0 = 0; k0 < 8; ++k0) {
      f16x8 xf[4];
      #pragma unroll
      for (int nt = 0; nt < 4; ++nt)
        xf[nt] = *(const f16x8*)&A[(nt * 16 + c16) * A_STRIDE + k0 * 32 + q * 8];
      f16x8 w0 = *(const f16x8*)&Wx[(c16) * 256 + k0 * 32 + q * 8];
      f16x8 w1 = *(const f16x8*)&Wx[(16 + c16) * 256 + k0 * 32 + q * 8];
      #pragma unroll
      for (int nt = 0; nt < 4; ++nt) {
        ac[0][nt] = __builtin_amdgcn_mfma_f32_16x16x32_f16(w0, xf[nt], ac[0][nt], 0, 0, 0);
        ac[1][nt] = __builtin_amdgcn_mfma_f32_16x16x32_f16(w1, xf[nt], ac[1][nt], 0, 0, 0);
      }
    }
    __builtin_amdgcn_s_setprio(0);
    // bias (d = 16*md + 4*q + r) then regroup to operand frags
    #pragma unroll
    for (int md = 0; md < 2; ++md) {
      float4 bb = *(const float4*)&bqkv[256 * pass + 32 * wv + md * 16 + 4 * q];
      #pragma unroll
      for (int nt = 0; nt < 4; ++nt) {
        ac[md][nt][0] += bb.x; ac[md][nt][1] += bb.y;
        ac[md][nt][2] += bb.z; ac[md][nt][3] += bb.w;
      }
    }
    #pragma unroll
    for (int nt = 0; nt < 4; ++nt) {
      f16x8 f = regroup(packh2(ac[0][nt][0], ac[0][nt][1]), packh2(ac[0][nt][2], ac[0][nt][3]),
                        packh2(ac[1][nt][0], ac[1][nt][1]), packh2(ac[1][nt][2], ac[1][nt][3]),
                        c16, q);
      if (pass == 0) qf[nt] = f; else kf[nt] = f;
    }
  }

  // ---- stage 3 (fused per nt): S^T col = K.Q^T, softmax, O^T col = V^T.P^T ----
  // Per-nt fusion keeps only one S column (16 regs) + transient pp (8 regs) live.
  f32x4 O[2][4];     // [md(d)][nt(t)]
  float rinv[4];
  {
    const float kExpScale = 0.25506973288423525f;  // (1/sqrt(32)) * log2(e)
    #pragma unroll
    for (int nt = 0; nt < 4; ++nt) {
      f32x4 S[4];
      __builtin_amdgcn_s_setprio(1);
      #pragma unroll
      for (int mu = 0; mu < 4; ++mu)
        S[mu] = __builtin_amdgcn_mfma_f32_16x16x32_f16(
            kf[mu], qf[nt], (f32x4){0.f,0.f,0.f,0.f}, 0, 0, 0);
      __builtin_amdgcn_s_setprio(0);

      float mx = S[0][0];
      #pragma unroll
      for (int mu = 0; mu < 4; ++mu)
        #pragma unroll
        for (int r = 0; r < 4; ++r)
          mx = fmaxf(mx, S[mu][r]);
      mx = fmaxf(mx, __shfl_xor(mx, 16));
      mx = fmaxf(mx, __shfl_xor(mx, 32));
      float sum = 0.f;
      #pragma unroll
      for (int mu = 0; mu < 4; ++mu)
        #pragma unroll
        for (int r = 0; r < 4; ++r) {
          float e = exp2f((S[mu][r] - mx) * kExpScale);
          S[mu][r] = e; sum += e;
        }
      sum += __shfl_xor(sum, 16);
      sum += __shfl_xor(sum, 32);
      rinv[nt] = 1.0f / sum;

      float pp[4][2];
      #pragma unroll
      for (int mu = 0; mu < 4; ++mu) {
        pp[mu][0] = packh2(S[mu][0], S[mu][1]);
        pp[mu][1] = packh2(S[mu][2], S[mu][3]);
      }
      O[0][nt] = (f32x4){0.f,0.f,0.f,0.f};
      O[1][nt] = (f32x4){0.f,0.f,0.f,0.f};
      #pragma unroll
      for (int kk = 0; kk < 2; ++kk) {
        f16x8 pf = regroup(pp[2*kk][0], pp[2*kk][1], pp[2*kk+1][0], pp[2*kk+1][1], c16, q);
        __builtin_amdgcn_s_setprio(1);
        O[0][nt] = __builtin_amdgcn_mfma_f32_16x16x32_f16(vf[0][kk], pf, O[0][nt], 0, 0, 0);
        O[1][nt] = __builtin_amdgcn_mfma_f32_16x16x32_f16(vf[1][kk], pf, O[1][nt], 0, 0, 0);
        __builtin_amdgcn_s_setprio(0);
      }
    }
  }

  // A is dead (last read in stage 2a). Reuse as ao[t][c].
  __syncthreads();
  {
    #pragma unroll
    for (int md = 0; md < 2; ++md)
      #pragma unroll
      for (int nt = 0; nt < 4; ++nt) {
        int t = nt * 16 + c16;
        int c = 32 * wv + md * 16 + 4 * q;
        *(float*)&A[t * A_STRIDE + c]     = packh2(O[md][nt][0] * rinv[nt], O[md][nt][1] * rinv[nt]);
        *(float*)&A[t * A_STRIDE + c + 2] = packh2(O[md][nt][2] * rinv[nt], O[md][nt][3] * rinv[nt]);
      }
  }
  __syncthreads();

  // ---- stage 4: proj via swapped GEMM  D[e][t] = W_p . ao^T + direct store ----
  {
    f32x4 ap[2][4];   // [me][nt]
    #pragma unroll
    for (int me = 0; me < 2; ++me)
      #pragma unroll
      for (int nt = 0; nt < 4; ++nt)
        ap[me][nt] = (f32x4){0.f,0.f,0.f,0.f};
    const _Float16* Wp = Wh + (size_t)768 * 256 + (size_t)(32 * wv) * 256;
    __builtin_amdgcn_s_setprio(1);
    #pragma unroll
    for (int k0 = 0; k0 < 8; ++k0) {
      f16x8 af[4];
      #pragma unroll
      for (int nt = 0; nt < 4; ++nt)
        af[nt] = *(const f16x8*)&A[(nt * 16 + c16) * A_STRIDE + k0 * 32 + q * 8];
      f16x8 wp0 = *(const f16x8*)&Wp[(c16) * 256 + k0 * 32 + q * 8];
      f16x8 wp1 = *(const f16x8*)&Wp[(16 + c16) * 256 + k0 * 32 + q * 8];
      #pragma unroll
      for (int nt = 0; nt < 4; ++nt) {
        ap[0][nt] = __builtin_amdgcn_mfma_f32_16x16x32_f16(wp0, af[nt], ap[0][nt], 0, 0, 0);
        ap[1][nt] = __builtin_amdgcn_mfma_f32_16x16x32_f16(wp1, af[nt], ap[1][nt], 0, 0, 0);
      }
    }
    __builtin_amdgcn_s_setprio(0);
    #pragma unroll
    for (int me = 0; me < 2; ++me) {
      float4 bp = *(const float4*)&bproj[32 * wv + me * 16 + 4 * q];
      #pragma unroll
      for (int nt = 0; nt < 4; ++nt) {
        int t = nt * 16 + c16;
        size_t sp = xbase + (size_t)(t >> 3) * 128 + (t & 7);
        int e = 32 * wv + me * 16 + 4 * q;
        out[sp + (size_t)(e + 0) * 16384] = ap[me][nt][0] + bp.x;
        out[sp + (size_t)(e + 1) * 16384] = ap[me][nt][1] + bp.y;
        out[sp + (size_t)(e + 2) * 16384] = ap[me][nt][2] + bp.z;
        out[sp + (size_t)(e + 3) * 16384] = ap[me][nt][3] + bp.w;
      }
    }
  }
}

extern "C" void kernel_launch(void* const* d_in, const int* in_sizes, int n_in,
                              void* d_out, int out_size, void* d_ws, size_t ws_size,
                              hipStream_t stream) {
  (void)in_sizes; (void)n_in; (void)out_size; (void)ws_size;
  const float* x     = (const float*)d_in[0];
  const float* wqkv  = (const float*)d_in[1];
  const float* bqkv  = (const float*)d_in[2];
  const float* wproj = (const float*)d_in[3];
  const float* bproj = (const float*)d_in[4];
  float* out = (float*)d_out;
  _Float16* Wh = (_Float16*)d_ws;   // 768*256 + 256*256 f16 = 524288 B

  hipLaunchKernelGGL(convert_weights_kernel, dim3(256), dim3(256), 0, stream,
                     wqkv, wproj, Wh);
  hipLaunchKernelGGL(win_attn_kernel, dim3(4096), dim3(512), 0, stream,
                     x, Wh, bqkv, bproj, out);
}